// Round 6
// baseline (559.003 us; speedup 1.0000x reference)
//
#include <hip/hip_runtime.h>

#define BATCHN 2
#define SEQL   2048
#define DM     1024
#define DI     2048
#define DSN    16
#define MTOT   (BATCHN * SEQL)   // 4096
#define PADL   (SEQL + 3)        // 2051
#define NC     64                // scan chunks
#define CL     (SEQL / NC)       // 32
#define BCKS   8                 // bc split-K factor

typedef __attribute__((ext_vector_type(8))) __bf16 bf16x8;
typedef __attribute__((ext_vector_type(4))) float f32x4;

__device__ __forceinline__ unsigned short f2b(float f) {
    union { float f; unsigned u; } v; v.f = f;
    unsigned r = v.u + 0x7FFF + ((v.u >> 16) & 1);
    return (unsigned short)(r >> 16);
}
__device__ __forceinline__ float b2f(unsigned short b) {
    union { float f; unsigned u; } v; v.u = ((unsigned)b) << 16;
    return v.f;
}

__device__ __forceinline__ void gl_lds16(const void* g, void* l) {
    __builtin_amdgcn_global_load_lds(
        (const __attribute__((address_space(1))) unsigned int*)g,
        (__attribute__((address_space(3))) unsigned int*)l, 16, 0, 0);
}

// XCD-aware block swizzle: 8 XCDs arranged 2 (x) x 4 (y) over the tile grid;
// each XCD covers a contiguous rectangle. Requires gx%2==0, gy%4==0.
__device__ __forceinline__ void swz(int& bx, int& by) {
    int gx = gridDim.x, gy = gridDim.y;
    int lin = blockIdx.y * gx + blockIdx.x;
    int xcd = lin & 7, k = lin >> 3;
    int rw = gx >> 1, rh = gy >> 2;
    by = (xcd >> 1) * rh + k / rw;
    bx = (xcd & 1) * rw + k % rw;
}

// ---------------- merged convert kernels ----------------
// x [b][l][c] fp32 -> xpad [b][3+l][c] bf16, plus zero the 3 lead rows.
#define NB_XCVT (MTOT * DM / 4 / 256)   // 4096
__global__ void cvt_x_all(const float* __restrict__ src, unsigned short* __restrict__ dst) {
    int blk = blockIdx.x;
    if (blk < NB_XCVT) {
        int i = blk * 256 + threadIdx.x;
        int b = i >> 19;
        float4 v = ((const float4*)src)[i];
        ushort4 o;
        o.x = f2b(v.x); o.y = f2b(v.y); o.z = f2b(v.z); o.w = f2b(v.w);
        ((ushort4*)dst)[i + (b + 1) * (3 * DM / 4)] = o;
    } else {
        int i = (blk - NB_XCVT) * 256 + threadIdx.x;
        if (i < BATCHN * 3 * DM) {
            int b = i / (3 * DM);
            int r = i % (3 * DM);
            dst[(size_t)b * PADL * DM + r] = 0;
        }
    }
}

// All weight converts in one region-dispatched kernel.
#define NB_CONVW (DI * DI / 256)           // 16384
#define NB_TP    ((DM / 32) * (DI / 32))   // 2048
#define NB_IPZ   (DI * DM / 4 / 256)       // 2048
#define NB_DTW   (DI * DI / 4 / 256)       // 4096
#define NB_OW    (DM * DI / 4 / 256)       // 2048
#define NB_BW    (DSN * DI / 4 / 256 + 1)  // 33 (8192/256 = 32, pad safe)
__global__ void __launch_bounds__(256)
cvt_w_all(const float* __restrict__ convw, const float* __restrict__ ipw,
          const float* __restrict__ dtw, const float* __restrict__ ow,
          const float* __restrict__ bw, const float* __restrict__ cw,
          unsigned short* __restrict__ wk, unsigned short* __restrict__ Pt,
          unsigned short* __restrict__ ipz, unsigned short* __restrict__ dtwb,
          unsigned short* __restrict__ owb, unsigned short* __restrict__ bcb)
{
    __shared__ float tile[32][33];
    int blk = blockIdx.x;
    int t = threadIdx.x;
    if (blk < NB_CONVW) {
        // conv_w (O,I,4) fp32 -> 4 planes wk[k][o][i] bf16
        int i = blk * 256 + t;
        float4 v = ((const float4*)convw)[i];
        wk[0 * (size_t)DI * DI + i] = f2b(v.x);
        wk[1 * (size_t)DI * DI + i] = f2b(v.y);
        wk[2 * (size_t)DI * DI + i] = f2b(v.z);
        wk[3 * (size_t)DI * DI + i] = f2b(v.w);
        return;
    }
    blk -= NB_CONVW;
    if (blk < NB_TP) {
        // transpose-convert: ipw xc-half [i<2048][c<1024] fp32 -> Pt [c][i] bf16
        int ct = (blk & 31) * 32, it = (blk >> 5) * 32;
        int tx = t & 31, ty = t >> 5;   // 32 x 8
#pragma unroll
        for (int r = 0; r < 4; ++r)
            tile[ty + r * 8][tx] = ipw[(size_t)(it + ty + r * 8) * DM + ct + tx];
        __syncthreads();
#pragma unroll
        for (int r = 0; r < 4; ++r)
            Pt[(size_t)(ct + ty + r * 8) * DI + it + tx] = f2b(tile[tx][ty + r * 8]);
        return;
    }
    blk -= NB_TP;
    const float* src;
    unsigned short* dst;
    int n4;
    if (blk < NB_IPZ) {
        src = ipw + (size_t)DI * DM; dst = ipz; n4 = DI * DM / 4;
    } else if ((blk -= NB_IPZ) < NB_DTW) {
        src = dtw; dst = dtwb; n4 = DI * DI / 4;
    } else if ((blk -= NB_DTW) < NB_OW) {
        src = ow; dst = owb; n4 = DM * DI / 4;
    } else if ((blk -= NB_OW) < NB_BW) {
        src = bw; dst = bcb; n4 = DSN * DI / 4;
    } else {
        blk -= NB_BW;
        src = cw; dst = bcb + (size_t)DSN * DI; n4 = DSN * DI / 4;
    }
    int i = blk * 256 + t;
    if (i < n4) {
        float4 v = ((const float4*)src)[i];
        ushort4 o;
        o.x = f2b(v.x); o.y = f2b(v.y); o.z = f2b(v.z); o.w = f2b(v.w);
        ((ushort4*)dst)[i] = o;
    }
}

// ---------------- MFMA GEMM, B^T layout, XOR-swizzled LDS, XCD swizzle ----
// MODE 1: conv+z  A=xpad; bx<16: u-tiles (4 segs, B=mk planes, +conv_b -> u_bf)
//                          bx>=16: z-tiles (1 seg at +3, B=ipz -> z_bf)
// MODE 2: dt      A=u_bf, B=dtw [2048][2048], K=2048, sigmoid-clip -> dt_bf
// MODE 3: out     A=y_bf, B=ow [1024][2048], K=2048 -> d_out fp32
// MODE 4: mk-fuse A=wk plane z [2048][2048], B=Pt [1024][2048], K=2048 -> mk plane z bf16
template<int MODE>
__global__ void __launch_bounds__(256)
gemm_bt(const unsigned short* __restrict__ Abase,
        const unsigned short* __restrict__ Bbase,
        const unsigned short* __restrict__ B2base,
        const float* __restrict__ bias,
        unsigned short* __restrict__ out_bf,
        unsigned short* __restrict__ out_bf2,
        float* __restrict__ out_f,
        int K)
{
    __shared__ __align__(16) unsigned short As[128 * 64];
    __shared__ __align__(16) unsigned short Bs[128 * 64];

    const int t = threadIdx.x;
    const int lane = t & 63;
    const int wave = t >> 6;
    const int wm = wave & 1, wn = wave >> 1;
    int bx, by;
    swz(bx, by);
    bool isz = false;
    int n0;
    if (MODE == 1) { isz = bx >= 16; n0 = (bx & 15) * 128; }
    else n0 = bx * 128;
    const int m0 = by * 128;
    const int srow = t >> 3;                          // 0..31
    const int scol = (t & 7) * 8;                     // LDS physical col (bf16)
    const int gcol = (((t & 7) ^ (srow & 7))) * 8;    // swizzled global col

    f32x4 acc[4][4];
#pragma unroll
    for (int i = 0; i < 4; ++i)
#pragma unroll
        for (int j = 0; j < 4; ++j)
            acc[i][j] = f32x4{0.f, 0.f, 0.f, 0.f};

    const int nseg = (MODE == 1) ? (isz ? 1 : 4) : 1;
    for (int seg = 0; seg < nseg; ++seg) {
        const unsigned short* arow[4];
        const unsigned short* brow[4];
#pragma unroll
        for (int i = 0; i < 4; ++i) {
            int rg = m0 + srow + i * 32;
            if (MODE == 1) {
                int sh = isz ? 3 : seg;
                arow[i] = Abase + ((size_t)(rg >> 11) * PADL + (rg & 2047) + sh) * DM;
            } else if (MODE == 4) {
                arow[i] = Abase + (size_t)blockIdx.z * DI * DI + (size_t)rg * K;
            } else {
                arow[i] = Abase + (size_t)rg * K;
            }
            int ng = n0 + srow + i * 32;
            if (MODE == 1) {
                if (isz) brow[i] = B2base + (size_t)ng * DM;
                else     brow[i] = Bbase + (size_t)seg * DI * DM + (size_t)ng * DM;
            } else {
                brow[i] = Bbase + (size_t)ng * K;
            }
        }
        const int Kseg = (MODE == 1) ? DM : K;
        for (int k0 = 0; k0 < Kseg; k0 += 64) {
#pragma unroll
            for (int i = 0; i < 4; ++i)
                gl_lds16(arow[i] + k0 + gcol, &As[(size_t)(srow + i * 32) * 64 + scol]);
#pragma unroll
            for (int i = 0; i < 4; ++i)
                gl_lds16(brow[i] + k0 + gcol, &Bs[(size_t)(srow + i * 32) * 64 + scol]);
            __syncthreads();
            const int qa = (lane >> 4) * 8;
            const int am = lane & 15;
            const int sw = (am & 7) << 3;   // XOR swizzle on element col
#pragma unroll
            for (int kk = 0; kk < 64; kk += 32) {
                bf16x8 af[4], bfv[4];
#pragma unroll
                for (int i = 0; i < 4; ++i)
                    af[i] = *(const bf16x8*)&As[(wm * 64 + i * 16 + am) * 64 + ((kk + qa) ^ sw)];
#pragma unroll
                for (int j = 0; j < 4; ++j)
                    bfv[j] = *(const bf16x8*)&Bs[(wn * 64 + j * 16 + am) * 64 + ((kk + qa) ^ sw)];
#pragma unroll
                for (int i = 0; i < 4; ++i)
#pragma unroll
                    for (int j = 0; j < 4; ++j)
                        acc[i][j] = __builtin_amdgcn_mfma_f32_16x16x32_bf16(
                            af[i], bfv[j], acc[i][j], 0, 0, 0);
            }
            __syncthreads();
        }
    }

    // epilogue: row = m0 + wm*64 + i*16 + (lane>>4)*4 + r ; col = n0 + wn*64 + j*16 + (lane&15)
    const int erow0 = m0 + wm * 64;
    const int ecol0 = n0 + wn * 64 + (lane & 15);
    const int rq = (lane >> 4) * 4;
#pragma unroll
    for (int i = 0; i < 4; ++i) {
#pragma unroll
        for (int j = 0; j < 4; ++j) {
            int col = ecol0 + j * 16;
#pragma unroll
            for (int r = 0; r < 4; ++r) {
                int row = erow0 + i * 16 + rq + r;
                float v = acc[i][j][r];
                if (MODE == 1) {
                    if (isz) {
                        out_bf2[(size_t)row * DI + col] = f2b(v);
                    } else {
                        v += bias[col];
                        out_bf[(size_t)row * DI + col] = f2b(v);
                    }
                } else if (MODE == 2) {
                    v += bias[col];
                    float s = 1.f / (1.f + __expf(-v));
                    s = fminf(fmaxf(s, 1e-4f), 1.f);
                    out_bf[(size_t)row * DI + col] = f2b(s);
                } else if (MODE == 3) {
                    out_f[(size_t)row * DM + col] = v;
                } else { // MODE 4
                    out_bf[(size_t)blockIdx.z * DI * DM + (size_t)row * DM + col] = f2b(v);
                }
            }
        }
    }
}

// ---------------- B/C projection: MFMA split-K ----------------
__global__ void __launch_bounds__(256)
bc_mfma(const unsigned short* __restrict__ u,
        const unsigned short* __restrict__ w,
        float* __restrict__ pc)
{
    const int t = threadIdx.x;
    const int lane = t & 63;
    const int wave = t >> 6;
    const int ks = blockIdx.x;                    // 0..BCKS-1
    const int m0 = blockIdx.y * 128 + wave * 32;
    const int am = lane & 15, quad = lane >> 4;

    f32x4 acc[2][2];
#pragma unroll
    for (int i = 0; i < 2; ++i)
#pragma unroll
        for (int j = 0; j < 2; ++j)
            acc[i][j] = f32x4{0.f, 0.f, 0.f, 0.f};

    const int kbase = ks * (DI / BCKS);
    const unsigned short* ur0 = u + (size_t)(m0 + am) * DI;
    const unsigned short* ur1 = u + (size_t)(m0 + 16 + am) * DI;
    const unsigned short* wr0 = w + (size_t)am * DI;
    const unsigned short* wr1 = w + (size_t)(16 + am) * DI;
#pragma unroll 2
    for (int kk = 0; kk < DI / BCKS; kk += 32) {
        int k = kbase + kk + quad * 8;
        bf16x8 a0 = *(const bf16x8*)(ur0 + k);
        bf16x8 a1 = *(const bf16x8*)(ur1 + k);
        bf16x8 b0 = *(const bf16x8*)(wr0 + k);
        bf16x8 b1 = *(const bf16x8*)(wr1 + k);
        acc[0][0] = __builtin_amdgcn_mfma_f32_16x16x32_bf16(a0, b0, acc[0][0], 0, 0, 0);
        acc[0][1] = __builtin_amdgcn_mfma_f32_16x16x32_bf16(a0, b1, acc[0][1], 0, 0, 0);
        acc[1][0] = __builtin_amdgcn_mfma_f32_16x16x32_bf16(a1, b0, acc[1][0], 0, 0, 0);
        acc[1][1] = __builtin_amdgcn_mfma_f32_16x16x32_bf16(a1, b1, acc[1][1], 0, 0, 0);
    }
    float* base = pc + (size_t)ks * MTOT * 32;
#pragma unroll
    for (int i = 0; i < 2; ++i)
#pragma unroll
        for (int j = 0; j < 2; ++j)
#pragma unroll
            for (int r = 0; r < 4; ++r) {
                int row = m0 + i * 16 + quad * 4 + r;
                int col = j * 16 + am;
                base[(size_t)row * 32 + col] = acc[i][j][r];
            }
}

__global__ void __launch_bounds__(256)
bc_reduce(const float* __restrict__ pc, float* __restrict__ outf)
{
    int i = blockIdx.x * 256 + threadIdx.x;       // float4 index, 32768 total
    const float4* p4 = (const float4*)pc;
    float4 s = p4[i];
#pragma unroll
    for (int ks = 1; ks < BCKS; ++ks) {
        float4 v = p4[(size_t)ks * (MTOT * 8) + i];
        s.x += v.x; s.y += v.y; s.z += v.z; s.w += v.w;
    }
    ((float4*)outf)[i] = s;
}

// ---------------- chunked selective scan ----------------
// Phase 1: per (b,d,chunk) lane, all 16 n in registers.
__global__ void __launch_bounds__(256)
scan_p1(const unsigned short* __restrict__ dt_bf,
        const unsigned short* __restrict__ u_bf,
        const float* __restrict__ bcf,
        const float* __restrict__ A_log,
        float* __restrict__ Pbuf,
        float* __restrict__ Sbuf)
{
    const int t = threadIdx.x;
    const int blk = blockIdx.x;          // 1024 = c(64) x dh(8) x b(2)
    const int c  = blk & (NC - 1);
    const int dh = (blk >> 6) & 7;
    const int b  = blk >> 9;
    const int d  = dh * 256 + t;

    float Adn[16];
    {
        const float4* ar = (const float4*)(A_log + (size_t)d * DSN);
#pragma unroll
        for (int q = 0; q < 4; ++q) {
            float4 v = ar[q];
            Adn[q * 4 + 0] = -__expf(v.x);
            Adn[q * 4 + 1] = -__expf(v.y);
            Adn[q * 4 + 2] = -__expf(v.z);
            Adn[q * 4 + 3] = -__expf(v.w);
        }
    }
    float s[16], P[16];
#pragma unroll
    for (int n = 0; n < 16; ++n) { s[n] = 0.f; P[n] = 1.f; }

    const size_t rowbase = (size_t)b * SEQL + (size_t)c * CL;
    for (int l0 = 0; l0 < CL; l0 += 4) {
        float dt4[4], u4[4];
#pragma unroll
        for (int j = 0; j < 4; ++j) {
            size_t rb = rowbase + l0 + j;
            dt4[j] = b2f(dt_bf[rb * DI + d]);
            u4[j] = b2f(u_bf[rb * DI + d]);
        }
#pragma unroll
        for (int j = 0; j < 4; ++j) {
            size_t rb = rowbase + l0 + j;
            const float4* Br = (const float4*)(bcf + rb * 32);
            float Bn[16];
#pragma unroll
            for (int q = 0; q < 4; ++q) {
                float4 v = Br[q];
                Bn[q * 4 + 0] = v.x; Bn[q * 4 + 1] = v.y;
                Bn[q * 4 + 2] = v.z; Bn[q * 4 + 3] = v.w;
            }
            float dt = dt4[j];
            float dBu = dt * u4[j];
#pragma unroll
            for (int n = 0; n < 16; ++n) {
                float x = dt * Adn[n];
                x = fminf(fmaxf(x, -5.f), 5.f);
                float dA = __expf(x);
                P[n] *= dA;
                s[n] = dA * s[n] + (dBu * Bn[n] + 1e-6f);
            }
        }
    }
    size_t ob = (((size_t)c * BATCHN + b) * DI + d) * DSN;
#pragma unroll
    for (int q = 0; q < 4; ++q) {
        ((float4*)(Pbuf + ob))[q] = make_float4(P[q*4], P[q*4+1], P[q*4+2], P[q*4+3]);
        ((float4*)(Sbuf + ob))[q] = make_float4(s[q*4], s[q*4+1], s[q*4+2], s[q*4+3]);
    }
}

// Phase 2: serial combine across chunks per (b,d,n). I[c] = incoming state.
__global__ void __launch_bounds__(256)
scan_p2(const float* __restrict__ Pbuf,
        const float* __restrict__ Sbuf,
        float* __restrict__ Ibuf)
{
    const int i = blockIdx.x * 256 + threadIdx.x;  // (b*DI+d)*16+n, 65536
    const int stride = BATCHN * DI * DSN;          // 65536
    float s = 0.f;
    for (int c0 = 0; c0 < NC; c0 += 8) {
        float Pv[8], Sv[8];
#pragma unroll
        for (int j = 0; j < 8; ++j) {
            size_t idx = (size_t)(c0 + j) * stride + i;
            Pv[j] = Pbuf[idx];
            Sv[j] = Sbuf[idx];
        }
#pragma unroll
        for (int j = 0; j < 8; ++j) {
            size_t idx = (size_t)(c0 + j) * stride + i;
            Ibuf[idx] = s;
            s = Pv[j] * s + Sv[j];
        }
    }
}

// Phase 3: re-run chunk from correct initial state, emit y (in-register n-sum).
__global__ void __launch_bounds__(256)
scan_p3(const unsigned short* __restrict__ dt_bf,
        const unsigned short* __restrict__ u_bf,
        const float* __restrict__ bcf,
        const unsigned short* __restrict__ z_bf,
        const float* __restrict__ A_log,
        const float* __restrict__ Dvec,
        const float* __restrict__ Ibuf,
        unsigned short* __restrict__ y_bf)
{
    const int t = threadIdx.x;
    const int blk = blockIdx.x;
    const int c  = blk & (NC - 1);
    const int dh = (blk >> 6) & 7;
    const int b  = blk >> 9;
    const int d  = dh * 256 + t;

    float Adn[16];
    {
        const float4* ar = (const float4*)(A_log + (size_t)d * DSN);
#pragma unroll
        for (int q = 0; q < 4; ++q) {
            float4 v = ar[q];
            Adn[q * 4 + 0] = -__expf(v.x);
            Adn[q * 4 + 1] = -__expf(v.y);
            Adn[q * 4 + 2] = -__expf(v.z);
            Adn[q * 4 + 3] = -__expf(v.w);
        }
    }
    const float Dd = Dvec[d];
    float s[16];
    {
        size_t ib = (((size_t)c * BATCHN + b) * DI + d) * DSN;
#pragma unroll
        for (int q = 0; q < 4; ++q) {
            float4 v = ((const float4*)(Ibuf + ib))[q];
            s[q * 4 + 0] = v.x; s[q * 4 + 1] = v.y;
            s[q * 4 + 2] = v.z; s[q * 4 + 3] = v.w;
        }
    }

    const size_t rowbase = (size_t)b * SEQL + (size_t)c * CL;
    for (int l0 = 0; l0 < CL; l0 += 4) {
        float dt4[4], u4[4], z4[4];
#pragma unroll
        for (int j = 0; j < 4; ++j) {
            size_t rb = rowbase + l0 + j;
            dt4[j] = b2f(dt_bf[rb * DI + d]);
            u4[j] = b2f(u_bf[rb * DI + d]);
            z4[j] = b2f(z_bf[rb * DI + d]);
        }
#pragma unroll
        for (int j = 0; j < 4; ++j) {
            size_t rb = rowbase + l0 + j;
            const float4* Br = (const float4*)(bcf + rb * 32);
            float Bn[16], Cn[16];
#pragma unroll
            for (int q = 0; q < 4; ++q) {
                float4 v = Br[q];
                Bn[q * 4 + 0] = v.x; Bn[q * 4 + 1] = v.y;
                Bn[q * 4 + 2] = v.z; Bn[q * 4 + 3] = v.w;
                float4 w = Br[q + 4];
                Cn[q * 4 + 0] = w.x; Cn[q * 4 + 1] = w.y;
                Cn[q * 4 + 2] = w.z; Cn[q * 4 + 3] = w.w;
            }
            float dt = dt4[j];
            float dBu = dt * u4[j];
            float y = 0.f;
#pragma unroll
            for (int n = 0; n < 16; ++n) {
                float x = dt * Adn[n];
                x = fminf(fmaxf(x, -5.f), 5.f);
                float dA = __expf(x);
                s[n] = dA * s[n] + (dBu * Bn[n] + 1e-6f);
                y += s[n] * Cn[n];
            }
            y += Dd * u4[j];
            float zz = z4[j];
            y *= zz / (1.f + __expf(-zz));
            y_bf[rb * DI + d] = f2b(y);
        }
    }
}

// ---------------- launch ----------------
extern "C" void kernel_launch(void* const* d_in, const int* in_sizes, int n_in,
                              void* d_out, int out_size, void* d_ws, size_t ws_size,
                              hipStream_t stream) {
    const float* x     = (const float*)d_in[0];
    const float* ipw   = (const float*)d_in[1];
    const float* convw = (const float*)d_in[2];
    const float* convb = (const float*)d_in[3];
    const float* dtw   = (const float*)d_in[4];
    const float* dtb   = (const float*)d_in[5];
    const float* alog  = (const float*)d_in[6];
    const float* dvec  = (const float*)d_in[7];
    const float* bw    = (const float*)d_in[8];
    const float* cwm   = (const float*)d_in[9];
    const float* ow    = (const float*)d_in[10];
    float* out = (float*)d_out;

    char* ws = (char*)d_ws;
    size_t off = 0;
    auto carve = [&](size_t bytes) {
        char* p = ws + off;
        off += (bytes + 255) & ~(size_t)255;
        return p;
    };
    unsigned short* xpad   = (unsigned short*)carve((size_t)BATCHN * PADL * DM * 2);
    unsigned short* ipz_bf = (unsigned short*)carve((size_t)DI * DM * 2);
    unsigned short* Pt_bf  = (unsigned short*)carve((size_t)DM * DI * 2);
    unsigned short* wk_bf  = (unsigned short*)carve((size_t)4 * DI * DI * 2);
    unsigned short* mk_bf  = (unsigned short*)carve((size_t)4 * DI * DM * 2);
    unsigned short* dtw_bf = (unsigned short*)carve((size_t)DI * DI * 2);
    unsigned short* ow_bf  = (unsigned short*)carve((size_t)DM * DI * 2);
    unsigned short* bc_bf  = (unsigned short*)carve((size_t)2 * DSN * DI * 2);
    unsigned short* z_bf   = (unsigned short*)carve((size_t)MTOT * DI * 2);
    unsigned short* u_bf   = (unsigned short*)carve((size_t)MTOT * DI * 2);
    unsigned short* dt_bf  = (unsigned short*)carve((size_t)MTOT * DI * 2);
    float*          bc_f   = (float*)carve((size_t)MTOT * 2 * DSN * 4);
    unsigned short* y_bf   = (unsigned short*)carve((size_t)MTOT * DI * 2);
    float*          Pbuf   = (float*)carve((size_t)NC * BATCHN * DI * DSN * 4);
    float*          Sbuf   = (float*)carve((size_t)NC * BATCHN * DI * DSN * 4);
    float*          Ibuf   = (float*)carve((size_t)NC * BATCHN * DI * DSN * 4);
    float*          pc_f   = (float*)carve((size_t)BCKS * MTOT * 32 * 4);

    // converts (2 kernels)
    cvt_x_all<<<NB_XCVT + (BATCHN * 3 * DM + 255) / 256, 256, 0, stream>>>(x, xpad);
    {
        int nb = NB_CONVW + NB_TP + NB_IPZ + NB_DTW + NB_OW + 2 * NB_BW;
        cvt_w_all<<<nb, 256, 0, stream>>>(convw, ipw, dtw, ow, bw, cwm,
                                          wk_bf, Pt_bf, ipz_bf, dtw_bf, ow_bf, bc_bf);
    }

    // mk-fuse: Mk = W_k @ P_xc   [2048][1024] x4 planes
    gemm_bt<4><<<dim3(8, 16, 4), 256, 0, stream>>>(wk_bf, Pt_bf, nullptr, nullptr, mk_bf, nullptr, nullptr, DI);
    // conv + z-proj merged: bx<16 -> u (4 segs, mk); bx>=16 -> z (1 seg, ipz)
    gemm_bt<1><<<dim3(32, 32), 256, 0, stream>>>(xpad, mk_bf, ipz_bf, convb, u_bf, z_bf, nullptr, DM);
    // B/C projection: MFMA split-K + reduce
    bc_mfma<<<dim3(BCKS, MTOT / 128), 256, 0, stream>>>(u_bf, bc_bf, pc_f);
    bc_reduce<<<MTOT * 32 / 4 / 256, 256, 0, stream>>>(pc_f, bc_f);
    // dt projection + sigmoid/clip -> bf16
    gemm_bt<2><<<dim3(16, 32), 256, 0, stream>>>(u_bf, dtw_bf, nullptr, dtb, dt_bf, nullptr, nullptr, DI);
    // chunked scan
    scan_p1<<<BATCHN * 8 * NC, 256, 0, stream>>>(dt_bf, u_bf, bc_f, alog, Pbuf, Sbuf);
    scan_p2<<<BATCHN * DI * DSN / 256, 256, 0, stream>>>(Pbuf, Sbuf, Ibuf);
    scan_p3<<<BATCHN * 8 * NC, 256, 0, stream>>>(dt_bf, u_bf, bc_f, z_bf, alog, dvec, Ibuf, y_bf);
    // out projection
    gemm_bt<3><<<dim3(8, 32), 256, 0, stream>>>(y_bf, ow_bf, nullptr, nullptr, nullptr, nullptr, out, DI);
}

// Round 7
// 473.020 us; speedup vs baseline: 1.1818x; 1.1818x over previous
//
#include <hip/hip_runtime.h>

#define BATCHN 2
#define SEQL   2048
#define DM     1024
#define DI     2048
#define DSN    16
#define MTOT   (BATCHN * SEQL)   // 4096
#define PADL   (SEQL + 3)        // 2051
#define NC     64                // scan chunks
#define CL     (SEQL / NC)       // 32
#define BCKS   8                 // bc split-K factor

typedef __attribute__((ext_vector_type(8))) __bf16 bf16x8;
typedef __attribute__((ext_vector_type(4))) float f32x4;

__device__ __forceinline__ unsigned short f2b(float f) {
    union { float f; unsigned u; } v; v.f = f;
    unsigned r = v.u + 0x7FFF + ((v.u >> 16) & 1);
    return (unsigned short)(r >> 16);
}
__device__ __forceinline__ float b2f(unsigned short b) {
    union { float f; unsigned u; } v; v.u = ((unsigned)b) << 16;
    return v.f;
}

__device__ __forceinline__ void gl_lds16(const void* g, void* l) {
    __builtin_amdgcn_global_load_lds(
        (const __attribute__((address_space(1))) unsigned int*)g,
        (__attribute__((address_space(3))) unsigned int*)l, 16, 0, 0);
}

// XCD-aware block swizzle: 8 XCDs arranged 2 (x) x 4 (y) over the tile grid;
// each XCD covers a contiguous rectangle. Requires gx%2==0, gy%4==0.
// NOTE (R6 post-mortem): only valid when all blocks have equal work —
// mixing heavy/light block types splits them onto disjoint XCDs (2x tail).
__device__ __forceinline__ void swz(int& bx, int& by) {
    int gx = gridDim.x, gy = gridDim.y;
    int lin = blockIdx.y * gx + blockIdx.x;
    int xcd = lin & 7, k = lin >> 3;
    int rw = gx >> 1, rh = gy >> 2;
    by = (xcd >> 1) * rh + k / rw;
    bx = (xcd & 1) * rw + k % rw;
}

// ---------------- merged convert kernels ----------------
// x [b][l][c] fp32 -> xpad [b][3+l][c] bf16, plus zero the 3 lead rows.
#define NB_XCVT (MTOT * DM / 4 / 256)   // 4096
__global__ void cvt_x_all(const float* __restrict__ src, unsigned short* __restrict__ dst) {
    int blk = blockIdx.x;
    if (blk < NB_XCVT) {
        int i = blk * 256 + threadIdx.x;
        int b = i >> 19;
        float4 v = ((const float4*)src)[i];
        ushort4 o;
        o.x = f2b(v.x); o.y = f2b(v.y); o.z = f2b(v.z); o.w = f2b(v.w);
        ((ushort4*)dst)[i + (b + 1) * (3 * DM / 4)] = o;
    } else {
        int i = (blk - NB_XCVT) * 256 + threadIdx.x;
        if (i < BATCHN * 3 * DM) {
            int b = i / (3 * DM);
            int r = i % (3 * DM);
            dst[(size_t)b * PADL * DM + r] = 0;
        }
    }
}

// All weight converts in one region-dispatched kernel.
#define NB_CONVW (DI * DI / 256)           // 16384
#define NB_TP    ((DM / 32) * (DI / 32))   // 2048
#define NB_IPZ   (DI * DM / 4 / 256)       // 2048
#define NB_DTW   (DI * DI / 4 / 256)       // 4096
#define NB_OW    (DM * DI / 4 / 256)       // 2048
#define NB_BW    (DSN * DI / 4 / 256 + 1)  // 33
__global__ void __launch_bounds__(256)
cvt_w_all(const float* __restrict__ convw, const float* __restrict__ ipw,
          const float* __restrict__ dtw, const float* __restrict__ ow,
          const float* __restrict__ bw, const float* __restrict__ cw,
          unsigned short* __restrict__ wk, unsigned short* __restrict__ Pt,
          unsigned short* __restrict__ ipz, unsigned short* __restrict__ dtwb,
          unsigned short* __restrict__ owb, unsigned short* __restrict__ bcb)
{
    __shared__ float tile[32][33];
    int blk = blockIdx.x;
    int t = threadIdx.x;
    if (blk < NB_CONVW) {
        int i = blk * 256 + t;
        float4 v = ((const float4*)convw)[i];
        wk[0 * (size_t)DI * DI + i] = f2b(v.x);
        wk[1 * (size_t)DI * DI + i] = f2b(v.y);
        wk[2 * (size_t)DI * DI + i] = f2b(v.z);
        wk[3 * (size_t)DI * DI + i] = f2b(v.w);
        return;
    }
    blk -= NB_CONVW;
    if (blk < NB_TP) {
        int ct = (blk & 31) * 32, it = (blk >> 5) * 32;
        int tx = t & 31, ty = t >> 5;   // 32 x 8
#pragma unroll
        for (int r = 0; r < 4; ++r)
            tile[ty + r * 8][tx] = ipw[(size_t)(it + ty + r * 8) * DM + ct + tx];
        __syncthreads();
#pragma unroll
        for (int r = 0; r < 4; ++r)
            Pt[(size_t)(ct + ty + r * 8) * DI + it + tx] = f2b(tile[tx][ty + r * 8]);
        return;
    }
    blk -= NB_TP;
    const float* src;
    unsigned short* dst;
    int n4;
    if (blk < NB_IPZ) {
        src = ipw + (size_t)DI * DM; dst = ipz; n4 = DI * DM / 4;
    } else if ((blk -= NB_IPZ) < NB_DTW) {
        src = dtw; dst = dtwb; n4 = DI * DI / 4;
    } else if ((blk -= NB_DTW) < NB_OW) {
        src = ow; dst = owb; n4 = DM * DI / 4;
    } else if ((blk -= NB_OW) < NB_BW) {
        src = bw; dst = bcb; n4 = DSN * DI / 4;
    } else {
        blk -= NB_BW;
        src = cw; dst = bcb + (size_t)DSN * DI; n4 = DSN * DI / 4;
    }
    int i = blk * 256 + t;
    if (i < n4) {
        float4 v = ((const float4*)src)[i];
        ushort4 o;
        o.x = f2b(v.x); o.y = f2b(v.y); o.z = f2b(v.z); o.w = f2b(v.w);
        ((ushort4*)dst)[i] = o;
    }
}

// ---------------- MFMA GEMM, B^T layout, XOR-swizzled LDS, XCD swizzle ----
// MODE 0: z-proj   A=xpad(+3), B=ipz [2048][1024], K=1024 -> z_bf
// MODE 1: conv     A=xpad(+seg), B=mk planes [2048][1024], K=1024 x4segs, +conv_b -> u_bf
// MODE 2: dt       A=u_bf, B=dtw [2048][2048], K=2048, sigmoid-clip -> dt_bf
// MODE 3: out      A=y_bf, B=ow [1024][2048], K=2048 -> d_out fp32
// MODE 4: mk-fuse  A=wk plane z [2048][2048], B=Pt [1024][2048], K=2048 -> mk plane z bf16
template<int MODE>
__global__ void __launch_bounds__(256)
gemm_bt(const unsigned short* __restrict__ Abase,
        const unsigned short* __restrict__ Bbase,
        const float* __restrict__ bias,
        unsigned short* __restrict__ out_bf,
        float* __restrict__ out_f,
        int K)
{
    __shared__ __align__(16) unsigned short As[128 * 64];
    __shared__ __align__(16) unsigned short Bs[128 * 64];

    const int t = threadIdx.x;
    const int lane = t & 63;
    const int wave = t >> 6;
    const int wm = wave & 1, wn = wave >> 1;
    int bx, by;
    swz(bx, by);
    const int m0 = by * 128, n0 = bx * 128;
    const int srow = t >> 3;                          // 0..31
    const int scol = (t & 7) * 8;                     // LDS physical col (bf16)
    const int gcol = (((t & 7) ^ (srow & 7))) * 8;    // swizzled global col

    f32x4 acc[4][4];
#pragma unroll
    for (int i = 0; i < 4; ++i)
#pragma unroll
        for (int j = 0; j < 4; ++j)
            acc[i][j] = f32x4{0.f, 0.f, 0.f, 0.f};

    const int nseg = (MODE == 1) ? 4 : 1;
    for (int seg = 0; seg < nseg; ++seg) {
        const unsigned short* arow[4];
        const unsigned short* brow[4];
#pragma unroll
        for (int i = 0; i < 4; ++i) {
            int rg = m0 + srow + i * 32;
            if (MODE == 0) {
                arow[i] = Abase + ((size_t)(rg >> 11) * PADL + 3 + (rg & 2047)) * DM;
            } else if (MODE == 1) {
                arow[i] = Abase + ((size_t)(rg >> 11) * PADL + (rg & 2047) + seg) * DM;
            } else if (MODE == 4) {
                arow[i] = Abase + (size_t)blockIdx.z * DI * DI + (size_t)rg * K;
            } else {
                arow[i] = Abase + (size_t)rg * K;
            }
            int ng = n0 + srow + i * 32;
            if (MODE == 1)
                brow[i] = Bbase + (size_t)seg * DI * DM + (size_t)ng * DM;
            else
                brow[i] = Bbase + (size_t)ng * K;
        }
        const int Kseg = (MODE == 1) ? DM : K;
        for (int k0 = 0; k0 < Kseg; k0 += 64) {
#pragma unroll
            for (int i = 0; i < 4; ++i)
                gl_lds16(arow[i] + k0 + gcol, &As[(size_t)(srow + i * 32) * 64 + scol]);
#pragma unroll
            for (int i = 0; i < 4; ++i)
                gl_lds16(brow[i] + k0 + gcol, &Bs[(size_t)(srow + i * 32) * 64 + scol]);
            __syncthreads();
            const int qa = (lane >> 4) * 8;
            const int am = lane & 15;
            const int sw = (am & 7) << 3;   // XOR swizzle on element col
#pragma unroll
            for (int kk = 0; kk < 64; kk += 32) {
                bf16x8 af[4], bfv[4];
#pragma unroll
                for (int i = 0; i < 4; ++i)
                    af[i] = *(const bf16x8*)&As[(wm * 64 + i * 16 + am) * 64 + ((kk + qa) ^ sw)];
#pragma unroll
                for (int j = 0; j < 4; ++j)
                    bfv[j] = *(const bf16x8*)&Bs[(wn * 64 + j * 16 + am) * 64 + ((kk + qa) ^ sw)];
#pragma unroll
                for (int i = 0; i < 4; ++i)
#pragma unroll
                    for (int j = 0; j < 4; ++j)
                        acc[i][j] = __builtin_amdgcn_mfma_f32_16x16x32_bf16(
                            af[i], bfv[j], acc[i][j], 0, 0, 0);
            }
            __syncthreads();
        }
    }

    // epilogue: row = m0 + wm*64 + i*16 + (lane>>4)*4 + r ; col = n0 + wn*64 + j*16 + (lane&15)
    const int erow0 = m0 + wm * 64;
    const int ecol0 = n0 + wn * 64 + (lane & 15);
    const int rq = (lane >> 4) * 4;
#pragma unroll
    for (int i = 0; i < 4; ++i) {
#pragma unroll
        for (int j = 0; j < 4; ++j) {
            int col = ecol0 + j * 16;
#pragma unroll
            for (int r = 0; r < 4; ++r) {
                int row = erow0 + i * 16 + rq + r;
                float v = acc[i][j][r];
                if (MODE == 0) {
                    out_bf[(size_t)row * DI + col] = f2b(v);
                } else if (MODE == 1) {
                    v += bias[col];
                    out_bf[(size_t)row * DI + col] = f2b(v);
                } else if (MODE == 2) {
                    v += bias[col];
                    float s = 1.f / (1.f + __expf(-v));
                    s = fminf(fmaxf(s, 1e-4f), 1.f);
                    out_bf[(size_t)row * DI + col] = f2b(s);
                } else if (MODE == 3) {
                    out_f[(size_t)row * DM + col] = v;
                } else { // MODE 4
                    out_bf[(size_t)blockIdx.z * DI * DM + (size_t)row * DM + col] = f2b(v);
                }
            }
        }
    }
}

// ---------------- B/C projection: MFMA split-K ----------------
__global__ void __launch_bounds__(256)
bc_mfma(const unsigned short* __restrict__ u,
        const unsigned short* __restrict__ w,
        float* __restrict__ pc)
{
    const int t = threadIdx.x;
    const int lane = t & 63;
    const int wave = t >> 6;
    const int ks = blockIdx.x;                    // 0..BCKS-1
    const int m0 = blockIdx.y * 128 + wave * 32;
    const int am = lane & 15, quad = lane >> 4;

    f32x4 acc[2][2];
#pragma unroll
    for (int i = 0; i < 2; ++i)
#pragma unroll
        for (int j = 0; j < 2; ++j)
            acc[i][j] = f32x4{0.f, 0.f, 0.f, 0.f};

    const int kbase = ks * (DI / BCKS);
    const unsigned short* ur0 = u + (size_t)(m0 + am) * DI;
    const unsigned short* ur1 = u + (size_t)(m0 + 16 + am) * DI;
    const unsigned short* wr0 = w + (size_t)am * DI;
    const unsigned short* wr1 = w + (size_t)(16 + am) * DI;
#pragma unroll 2
    for (int kk = 0; kk < DI / BCKS; kk += 32) {
        int k = kbase + kk + quad * 8;
        bf16x8 a0 = *(const bf16x8*)(ur0 + k);
        bf16x8 a1 = *(const bf16x8*)(ur1 + k);
        bf16x8 b0 = *(const bf16x8*)(wr0 + k);
        bf16x8 b1 = *(const bf16x8*)(wr1 + k);
        acc[0][0] = __builtin_amdgcn_mfma_f32_16x16x32_bf16(a0, b0, acc[0][0], 0, 0, 0);
        acc[0][1] = __builtin_amdgcn_mfma_f32_16x16x32_bf16(a0, b1, acc[0][1], 0, 0, 0);
        acc[1][0] = __builtin_amdgcn_mfma_f32_16x16x32_bf16(a1, b0, acc[1][0], 0, 0, 0);
        acc[1][1] = __builtin_amdgcn_mfma_f32_16x16x32_bf16(a1, b1, acc[1][1], 0, 0, 0);
    }
    float* base = pc + (size_t)ks * MTOT * 32;
#pragma unroll
    for (int i = 0; i < 2; ++i)
#pragma unroll
        for (int j = 0; j < 2; ++j)
#pragma unroll
            for (int r = 0; r < 4; ++r) {
                int row = m0 + i * 16 + quad * 4 + r;
                int col = j * 16 + am;
                base[(size_t)row * 32 + col] = acc[i][j][r];
            }
}

__global__ void __launch_bounds__(256)
bc_reduce(const float* __restrict__ pc, float* __restrict__ outf)
{
    int i = blockIdx.x * 256 + threadIdx.x;       // float4 index, 32768 total
    const float4* p4 = (const float4*)pc;
    float4 s = p4[i];
#pragma unroll
    for (int ks = 1; ks < BCKS; ++ks) {
        float4 v = p4[(size_t)ks * (MTOT * 8) + i];
        s.x += v.x; s.y += v.y; s.z += v.z; s.w += v.w;
    }
    ((float4*)outf)[i] = s;
}

// ---------------- chunked selective scan ----------------
__global__ void __launch_bounds__(256)
scan_p1(const unsigned short* __restrict__ dt_bf,
        const unsigned short* __restrict__ u_bf,
        const float* __restrict__ bcf,
        const float* __restrict__ A_log,
        float* __restrict__ Pbuf,
        float* __restrict__ Sbuf)
{
    const int t = threadIdx.x;
    const int blk = blockIdx.x;          // 1024 = c(64) x dh(8) x b(2)
    const int c  = blk & (NC - 1);
    const int dh = (blk >> 6) & 7;
    const int b  = blk >> 9;
    const int d  = dh * 256 + t;

    float Adn[16];
    {
        const float4* ar = (const float4*)(A_log + (size_t)d * DSN);
#pragma unroll
        for (int q = 0; q < 4; ++q) {
            float4 v = ar[q];
            Adn[q * 4 + 0] = -__expf(v.x);
            Adn[q * 4 + 1] = -__expf(v.y);
            Adn[q * 4 + 2] = -__expf(v.z);
            Adn[q * 4 + 3] = -__expf(v.w);
        }
    }
    float s[16], P[16];
#pragma unroll
    for (int n = 0; n < 16; ++n) { s[n] = 0.f; P[n] = 1.f; }

    const size_t rowbase = (size_t)b * SEQL + (size_t)c * CL;
    for (int l0 = 0; l0 < CL; l0 += 4) {
        float dt4[4], u4[4];
#pragma unroll
        for (int j = 0; j < 4; ++j) {
            size_t rb = rowbase + l0 + j;
            dt4[j] = b2f(dt_bf[rb * DI + d]);
            u4[j] = b2f(u_bf[rb * DI + d]);
        }
#pragma unroll
        for (int j = 0; j < 4; ++j) {
            size_t rb = rowbase + l0 + j;
            const float4* Br = (const float4*)(bcf + rb * 32);
            float Bn[16];
#pragma unroll
            for (int q = 0; q < 4; ++q) {
                float4 v = Br[q];
                Bn[q * 4 + 0] = v.x; Bn[q * 4 + 1] = v.y;
                Bn[q * 4 + 2] = v.z; Bn[q * 4 + 3] = v.w;
            }
            float dt = dt4[j];
            float dBu = dt * u4[j];
#pragma unroll
            for (int n = 0; n < 16; ++n) {
                float x = dt * Adn[n];
                x = fminf(fmaxf(x, -5.f), 5.f);
                float dA = __expf(x);
                P[n] *= dA;
                s[n] = dA * s[n] + (dBu * Bn[n] + 1e-6f);
            }
        }
    }
    size_t ob = (((size_t)c * BATCHN + b) * DI + d) * DSN;
#pragma unroll
    for (int q = 0; q < 4; ++q) {
        ((float4*)(Pbuf + ob))[q] = make_float4(P[q*4], P[q*4+1], P[q*4+2], P[q*4+3]);
        ((float4*)(Sbuf + ob))[q] = make_float4(s[q*4], s[q*4+1], s[q*4+2], s[q*4+3]);
    }
}

__global__ void __launch_bounds__(256)
scan_p2(const float* __restrict__ Pbuf,
        const float* __restrict__ Sbuf,
        float* __restrict__ Ibuf)
{
    const int i = blockIdx.x * 256 + threadIdx.x;  // (b*DI+d)*16+n, 65536
    const int stride = BATCHN * DI * DSN;          // 65536
    float s = 0.f;
    for (int c0 = 0; c0 < NC; c0 += 8) {
        float Pv[8], Sv[8];
#pragma unroll
        for (int j = 0; j < 8; ++j) {
            size_t idx = (size_t)(c0 + j) * stride + i;
            Pv[j] = Pbuf[idx];
            Sv[j] = Sbuf[idx];
        }
#pragma unroll
        for (int j = 0; j < 8; ++j) {
            size_t idx = (size_t)(c0 + j) * stride + i;
            Ibuf[idx] = s;
            s = Pv[j] * s + Sv[j];
        }
    }
}

__global__ void __launch_bounds__(256)
scan_p3(const unsigned short* __restrict__ dt_bf,
        const unsigned short* __restrict__ u_bf,
        const float* __restrict__ bcf,
        const unsigned short* __restrict__ z_bf,
        const float* __restrict__ A_log,
        const float* __restrict__ Dvec,
        const float* __restrict__ Ibuf,
        unsigned short* __restrict__ y_bf)
{
    const int t = threadIdx.x;
    const int blk = blockIdx.x;
    const int c  = blk & (NC - 1);
    const int dh = (blk >> 6) & 7;
    const int b  = blk >> 9;
    const int d  = dh * 256 + t;

    float Adn[16];
    {
        const float4* ar = (const float4*)(A_log + (size_t)d * DSN);
#pragma unroll
        for (int q = 0; q < 4; ++q) {
            float4 v = ar[q];
            Adn[q * 4 + 0] = -__expf(v.x);
            Adn[q * 4 + 1] = -__expf(v.y);
            Adn[q * 4 + 2] = -__expf(v.z);
            Adn[q * 4 + 3] = -__expf(v.w);
        }
    }
    const float Dd = Dvec[d];
    float s[16];
    {
        size_t ib = (((size_t)c * BATCHN + b) * DI + d) * DSN;
#pragma unroll
        for (int q = 0; q < 4; ++q) {
            float4 v = ((const float4*)(Ibuf + ib))[q];
            s[q * 4 + 0] = v.x; s[q * 4 + 1] = v.y;
            s[q * 4 + 2] = v.z; s[q * 4 + 3] = v.w;
        }
    }

    const size_t rowbase = (size_t)b * SEQL + (size_t)c * CL;
    for (int l0 = 0; l0 < CL; l0 += 4) {
        float dt4[4], u4[4], z4[4];
#pragma unroll
        for (int j = 0; j < 4; ++j) {
            size_t rb = rowbase + l0 + j;
            dt4[j] = b2f(dt_bf[rb * DI + d]);
            u4[j] = b2f(u_bf[rb * DI + d]);
            z4[j] = b2f(z_bf[rb * DI + d]);
        }
#pragma unroll
        for (int j = 0; j < 4; ++j) {
            size_t rb = rowbase + l0 + j;
            const float4* Br = (const float4*)(bcf + rb * 32);
            float Bn[16], Cn[16];
#pragma unroll
            for (int q = 0; q < 4; ++q) {
                float4 v = Br[q];
                Bn[q * 4 + 0] = v.x; Bn[q * 4 + 1] = v.y;
                Bn[q * 4 + 2] = v.z; Bn[q * 4 + 3] = v.w;
                float4 w = Br[q + 4];
                Cn[q * 4 + 0] = w.x; Cn[q * 4 + 1] = w.y;
                Cn[q * 4 + 2] = w.z; Cn[q * 4 + 3] = w.w;
            }
            float dt = dt4[j];
            float dBu = dt * u4[j];
            float y = 0.f;
#pragma unroll
            for (int n = 0; n < 16; ++n) {
                float x = dt * Adn[n];
                x = fminf(fmaxf(x, -5.f), 5.f);
                float dA = __expf(x);
                s[n] = dA * s[n] + (dBu * Bn[n] + 1e-6f);
                y += s[n] * Cn[n];
            }
            y += Dd * u4[j];
            float zz = z4[j];
            y *= zz / (1.f + __expf(-zz));
            y_bf[rb * DI + d] = f2b(y);
        }
    }
}

// ---------------- launch ----------------
extern "C" void kernel_launch(void* const* d_in, const int* in_sizes, int n_in,
                              void* d_out, int out_size, void* d_ws, size_t ws_size,
                              hipStream_t stream) {
    const float* x     = (const float*)d_in[0];
    const float* ipw   = (const float*)d_in[1];
    const float* convw = (const float*)d_in[2];
    const float* convb = (const float*)d_in[3];
    const float* dtw   = (const float*)d_in[4];
    const float* dtb   = (const float*)d_in[5];
    const float* alog  = (const float*)d_in[6];
    const float* dvec  = (const float*)d_in[7];
    const float* bw    = (const float*)d_in[8];
    const float* cwm   = (const float*)d_in[9];
    const float* ow    = (const float*)d_in[10];
    float* out = (float*)d_out;

    char* ws = (char*)d_ws;
    size_t off = 0;
    auto carve = [&](size_t bytes) {
        char* p = ws + off;
        off += (bytes + 255) & ~(size_t)255;
        return p;
    };
    unsigned short* xpad   = (unsigned short*)carve((size_t)BATCHN * PADL * DM * 2);
    unsigned short* ipz_bf = (unsigned short*)carve((size_t)DI * DM * 2);
    unsigned short* Pt_bf  = (unsigned short*)carve((size_t)DM * DI * 2);
    unsigned short* wk_bf  = (unsigned short*)carve((size_t)4 * DI * DI * 2);
    unsigned short* mk_bf  = (unsigned short*)carve((size_t)4 * DI * DM * 2);
    unsigned short* dtw_bf = (unsigned short*)carve((size_t)DI * DI * 2);
    unsigned short* ow_bf  = (unsigned short*)carve((size_t)DM * DI * 2);
    unsigned short* bc_bf  = (unsigned short*)carve((size_t)2 * DSN * DI * 2);
    unsigned short* z_bf   = (unsigned short*)carve((size_t)MTOT * DI * 2);
    unsigned short* u_bf   = (unsigned short*)carve((size_t)MTOT * DI * 2);
    unsigned short* dt_bf  = (unsigned short*)carve((size_t)MTOT * DI * 2);
    float*          bc_f   = (float*)carve((size_t)MTOT * 2 * DSN * 4);
    unsigned short* y_bf   = (unsigned short*)carve((size_t)MTOT * DI * 2);
    float*          Pbuf   = (float*)carve((size_t)NC * BATCHN * DI * DSN * 4);
    float*          Sbuf   = (float*)carve((size_t)NC * BATCHN * DI * DSN * 4);
    float*          Ibuf   = (float*)carve((size_t)NC * BATCHN * DI * DSN * 4);
    float*          pc_f   = (float*)carve((size_t)BCKS * MTOT * 32 * 4);

    // converts (2 kernels)
    cvt_x_all<<<NB_XCVT + (BATCHN * 3 * DM + 255) / 256, 256, 0, stream>>>(x, xpad);
    {
        int nb = NB_CONVW + NB_TP + NB_IPZ + NB_DTW + NB_OW + 2 * NB_BW;
        cvt_w_all<<<nb, 256, 0, stream>>>(convw, ipw, dtw, ow, bw, cwm,
                                          wk_bf, Pt_bf, ipz_bf, dtw_bf, ow_bf, bc_bf);
    }

    // mk-fuse: Mk = W_k @ P_xc   [2048][1024] x4 planes
    gemm_bt<4><<<dim3(8, 16, 4), 256, 0, stream>>>(wk_bf, Pt_bf, nullptr, mk_bf, nullptr, DI);
    // z-proj: z = x @ ipz^T
    gemm_bt<0><<<dim3(16, 32), 256, 0, stream>>>(xpad, ipz_bf, nullptr, z_bf, nullptr, DM);
    // conv (fused): u = sum_k x[l-3+k] @ Mk^T + conv_b
    gemm_bt<1><<<dim3(16, 32), 256, 0, stream>>>(xpad, mk_bf, convb, u_bf, nullptr, DM);
    // B/C projection: MFMA split-K + reduce
    bc_mfma<<<dim3(BCKS, MTOT / 128), 256, 0, stream>>>(u_bf, bc_bf, pc_f);
    bc_reduce<<<MTOT * 32 / 4 / 256, 256, 0, stream>>>(pc_f, bc_f);
    // dt projection + sigmoid/clip -> bf16
    gemm_bt<2><<<dim3(16, 32), 256, 0, stream>>>(u_bf, dtw_bf, dtb, dt_bf, nullptr, DI);
    // chunked scan
    scan_p1<<<BATCHN * 8 * NC, 256, 0, stream>>>(dt_bf, u_bf, bc_f, alog, Pbuf, Sbuf);
    scan_p2<<<BATCHN * DI * DSN / 256, 256, 0, stream>>>(Pbuf, Sbuf, Ibuf);
    scan_p3<<<BATCHN * 8 * NC, 256, 0, stream>>>(dt_bf, u_bf, bc_f, z_bf, alog, dvec, Ibuf, y_bf);
    // out projection
    gemm_bt<3><<<dim3(8, 32), 256, 0, stream>>>(y_bf, ow_bf, nullptr, nullptr, out, DI);
}